// Round 8
// baseline (261.689 us; speedup 1.0000x reference)
//
#include <hip/hip_runtime.h>

#define TT   2048
#define BB   8
#define DD   1024
#define HD   64        // head dim d
#define MP1  9         // NM + 1
#define NTOK (TT*BB)   // 16384
#define CH   64        // chunk length
#define NC   32        // max chunks per segment
#define NSEG (BB*MP1)  // 72 segments
#define SEGCAP 2048    // max packed positions per segment
#define LDP  72        // padded LDS row stride (16B-aligned)

typedef __attribute__((ext_vector_type(8))) short bf16x8;
typedef __attribute__((ext_vector_type(4))) float f32x4;

union U8 { uint4 v; unsigned short s[8]; };

static __device__ __forceinline__ unsigned short f2bf(float f) {
  union { float f; unsigned u; } c; c.f = f;
  unsigned r = (c.u + 0x7FFF + ((c.u >> 16) & 1)) >> 16;   // RNE
  return (unsigned short)r;
}
static __device__ __forceinline__ float bf2f(unsigned short s) {
  union { unsigned u; float f; } c; c.u = ((unsigned)s) << 16;
  return c.f;
}

// ---------------------------------------------------------------
// prep: blocks [0,320) = weight transpose/cast; rest = gating
// ---------------------------------------------------------------
__global__ __launch_bounds__(256) void prep(
    const float* __restrict__ X,
    const float* __restrict__ Wq, const float* __restrict__ Wk,
    const float* __restrict__ Wv, const float* __restrict__ bq,
    const float* __restrict__ bk, const float* __restrict__ bv,
    const float* __restrict__ Wg, const float* __restrict__ bg,
    unsigned short* __restrict__ Wt, float* __restrict__ bcat,
    int2* __restrict__ idxb, float2* __restrict__ alfb,
    unsigned short* __restrict__ Xbf) {
  __shared__ float smem[8 * DD];
  const int tid = threadIdx.x;
  const int id = blockIdx.x;
  if (id < 320) {
    float (*tile)[65] = (float(*)[65])smem;
    const int n0 = (id % 20) * 64, k0 = (id / 20) * 64;
    const int c = tid & 63, rr = tid >> 6;
#pragma unroll 4
    for (int i = 0; i < 16; i++) {
      int kk = k0 + rr * 16 + i;
      int n  = n0 + c;
      float v = 0.f;
      if (n0 < 64)        v = Wq[kk * 64 + n];
      else if (n0 < 640)  v = Wk[kk * 576 + (n - 64)];
      else if (n0 < 1216) v = Wv[kk * 576 + (n - 640)];
      tile[rr * 16 + i][c] = v;
    }
    __syncthreads();
    const int lk = (tid & 15) * 4, ln = tid >> 4;
#pragma unroll
    for (int p = 0; p < 4; p++) {
      int nl = p * 16 + ln;
      ushort4 o;
      o.x = f2bf(tile[lk + 0][nl]); o.y = f2bf(tile[lk + 1][nl]);
      o.z = f2bf(tile[lk + 2][nl]); o.w = f2bf(tile[lk + 3][nl]);
      *(ushort4*)&Wt[(size_t)(n0 + nl) * DD + k0 + lk] = o;
    }
    if (id == 0) {
      for (int idx = tid; idx < 1280; idx += 256) {
        float b = 0.f;
        if (idx < 64)        b = bq[idx];
        else if (idx < 640)  b = bk[idx - 64];
        else if (idx < 1216) b = bv[idx - 640];
        bcat[idx] = b;
      }
    }
    return;
  }
  float* wgT = smem;
  for (int idx = tid; idx < 8 * DD; idx += 256) {
    int i = idx >> 3, j = idx & 7;
    wgT[j * DD + i] = Wg[idx];
  }
  __syncthreads();
  const int lane = tid & 63, wave = tid >> 6;
  const int base_tok = (id - 320) * 16 + wave * 4;
  for (int tk = 0; tk < 4; tk++) {
    const int tok = base_tok + tk;
    const float* xr = X + (size_t)tok * DD;
    unsigned short* xbr = Xbf + (size_t)tok * DD;
    float p[8] = {0.f,0.f,0.f,0.f,0.f,0.f,0.f,0.f};
#pragma unroll
    for (int it = 0; it < 4; it++) {
      int i = it * 256 + lane * 4;
      float4 x = *(const float4*)&xr[i];
      ushort4 o;
      o.x = f2bf(x.x); o.y = f2bf(x.y); o.z = f2bf(x.z); o.w = f2bf(x.w);
      *(ushort4*)&xbr[i] = o;
#pragma unroll
      for (int j = 0; j < 8; j++) {
        float4 wv = *(const float4*)&wgT[j * DD + i];
        p[j] += x.x * wv.x + x.y * wv.y + x.z * wv.z + x.w * wv.w;
      }
    }
#pragma unroll
    for (int j = 0; j < 8; j++) {
      float v = p[j];
#pragma unroll
      for (int off = 32; off > 0; off >>= 1) v += __shfl_xor(v, off);
      p[j] = v + bg[j];
    }
    if (lane == 0) {
      int i1 = 0; float z1 = p[0];
#pragma unroll
      for (int j = 1; j < 8; j++) if (p[j] > z1) { z1 = p[j]; i1 = j; }
      int i2 = -1; float z2 = -3.0e38f;
#pragma unroll
      for (int j = 0; j < 8; j++) if (j != i1 && p[j] > z2) { z2 = p[j]; i2 = j; }
      float e   = expf(z2 - z1);
      float inv = 1.0f / (1.0f + e);
      idxb[tok] = make_int2(i1 + 1, i2 + 1);
      alfb[tok] = make_float2(inv, e * inv);
    }
  }
}

// ---------------------------------------------------------------
// pack: per segment (b,m), time-ordered list of routed tokens.
// tlist (pad->0), alist (pad->0), seglen. One block per segment.
// ---------------------------------------------------------------
__global__ __launch_bounds__(256) void pack_kernel(
    const int2* __restrict__ idxb, const float2* __restrict__ alfb,
    int* __restrict__ tlist, float* __restrict__ alist,
    int* __restrict__ seglen) {
  const int seg = blockIdx.x;
  const int b = seg / MP1, m = seg % MP1;
  const int tid = threadIdx.x;
  int* tl = tlist + (size_t)seg * SEGCAP;
  float* al = alist + (size_t)seg * SEGCAP;
  if (m == 0) {
    for (int pos = tid; pos < TT; pos += 256) { tl[pos] = pos; al[pos] = 1.f; }
    if (tid == 0) seglen[seg] = TT;
    return;
  }
  __shared__ int flags[256];
  int base = 0;
  for (int r = 0; r < TT / 256; r++) {
    int t = r * 256 + tid;
    int2 ix = idxb[t * BB + b];
    int f = (ix.x == m || ix.y == m) ? 1 : 0;
    float2 af = alfb[t * BB + b];
    float alpha = (ix.x == m) ? af.x : af.y;
    flags[tid] = f;
    __syncthreads();
#pragma unroll
    for (int s = 1; s < 256; s <<= 1) {
      int v = (tid >= s) ? flags[tid - s] : 0;
      __syncthreads();
      flags[tid] += v;
      __syncthreads();
    }
    if (f) {
      int pos = base + flags[tid] - 1;
      tl[pos] = t;
      al[pos] = alpha;
    }
    base += flags[255];
    __syncthreads();
  }
  if (tid == 0) seglen[seg] = base;
  int Lpad = (base + 127) & ~127;
  for (int pos = base + tid; pos < Lpad; pos += 256) { tl[pos] = 0; al[pos] = 0.f; }
}

// ---------------------------------------------------------------
// proj_q: dense (16384 x 1024) @ (1024 x 64) -> Qb bf16 (+bias)
// BM=128, BN=64, 4 waves each 32x64
// ---------------------------------------------------------------
__global__ __launch_bounds__(256) void proj_q(
    const unsigned short* __restrict__ Xbf, const unsigned short* __restrict__ Wt,
    const float* __restrict__ bcat, unsigned short* __restrict__ Qb) {
  __shared__ unsigned short As[128 * 32];
  __shared__ unsigned short Bs[64 * 32];
  const int tid  = threadIdx.x;
  const int lane = tid & 63, w = tid >> 6;
  const int row0 = blockIdx.x * 128;
  const int lrow = lane >> 2, lk = (lane & 3) * 8;
  const int l15 = lane & 15, quad = lane >> 4, quad8 = quad * 8;
  f32x4 acc[2][4];
#pragma unroll
  for (int i = 0; i < 2; i++)
#pragma unroll
    for (int j = 0; j < 4; j++) acc[i][j] = (f32x4){0.f,0.f,0.f,0.f};
  for (int k0 = 0; k0 < DD; k0 += 32) {
    __syncthreads();
#pragma unroll
    for (int c = 0; c < 2; c++) {
      int r = w * 32 + c * 16 + lrow;
      __builtin_amdgcn_global_load_lds(
          (const __attribute__((address_space(1))) unsigned int*)(Xbf + (size_t)(row0 + r) * DD + k0 + lk),
          (__attribute__((address_space(3))) unsigned int*)(As + (w * 32 + c * 16) * 32),
          16, 0, 0);
    }
    __builtin_amdgcn_global_load_lds(
        (const __attribute__((address_space(1))) unsigned int*)(Wt + (size_t)(w * 16 + lrow) * DD + k0 + lk),
        (__attribute__((address_space(3))) unsigned int*)(Bs + w * 512),
        16, 0, 0);
    __syncthreads();
    bf16x8 af[2], bfr[4];
#pragma unroll
    for (int i = 0; i < 2; i++)
      af[i] = *(const bf16x8*)&As[(w * 32 + i * 16 + l15) * 32 + quad8];
#pragma unroll
    for (int j = 0; j < 4; j++)
      bfr[j] = *(const bf16x8*)&Bs[(j * 16 + l15) * 32 + quad8];
#pragma unroll
    for (int mi = 0; mi < 2; mi++)
#pragma unroll
      for (int ni = 0; ni < 4; ni++)
        acc[mi][ni] = __builtin_amdgcn_mfma_f32_16x16x32_bf16(af[mi], bfr[ni], acc[mi][ni], 0, 0, 0);
  }
#pragma unroll
  for (int ni = 0; ni < 4; ni++) {
    int col = ni * 16 + l15;
    float bias = bcat[col];
#pragma unroll
    for (int mi = 0; mi < 2; mi++) {
      int rbase = row0 + w * 32 + mi * 16 + quad * 4;
#pragma unroll
      for (int r = 0; r < 4; r++)
        Qb[(size_t)(rbase + r) * HD + col] = f2bf(acc[mi][ni][r] + bias);
    }
  }
}

// ---------------------------------------------------------------
// proj_kv: per-segment gathered GEMM -> packed K|V (128 cols)
// A rows gathered via tlist; pad rows zeroed in epilogue
// ---------------------------------------------------------------
__global__ __launch_bounds__(256) void proj_kv(
    const unsigned short* __restrict__ Xbf, const unsigned short* __restrict__ Wt,
    const float* __restrict__ bcat, const int* __restrict__ tlist,
    const int* __restrict__ seglen, unsigned short* __restrict__ KVp) {
  const int tile = blockIdx.x, seg = blockIdx.y;
  const int L = seglen[seg];
  if (tile * 128 >= L) return;
  const int b = seg / MP1, m = seg % MP1;
  __shared__ unsigned short As[128 * 32];
  __shared__ unsigned short Bs[128 * 32];
  const int tid  = threadIdx.x;
  const int lane = tid & 63, w = tid >> 6;
  const int lrow = lane >> 2, lk = (lane & 3) * 8;
  const int l15 = lane & 15, quad = lane >> 4, quad8 = quad * 8;
  const int wr = (w >> 1) * 64, wc = (w & 1) * 64;
  const int* tl = tlist + (size_t)seg * SEGCAP;
  int srcrow[2], nrow[2];
#pragma unroll
  for (int c = 0; c < 2; c++) {
    int rr = c * 64 + w * 16 + lrow;
    srcrow[c] = tl[tile * 128 + rr] * BB + b;
    nrow[c] = (rr < 64) ? (64 + m * 64 + rr) : (640 + m * 64 + (rr - 64));
  }
  f32x4 acc[4][4];
#pragma unroll
  for (int i = 0; i < 4; i++)
#pragma unroll
    for (int j = 0; j < 4; j++) acc[i][j] = (f32x4){0.f,0.f,0.f,0.f};
  for (int k0 = 0; k0 < DD; k0 += 32) {
    __syncthreads();
#pragma unroll
    for (int c = 0; c < 2; c++) {
      __builtin_amdgcn_global_load_lds(
          (const __attribute__((address_space(1))) unsigned int*)(Xbf + (size_t)srcrow[c] * DD + k0 + lk),
          (__attribute__((address_space(3))) unsigned int*)(As + c * 2048 + w * 512),
          16, 0, 0);
      __builtin_amdgcn_global_load_lds(
          (const __attribute__((address_space(1))) unsigned int*)(Wt + (size_t)nrow[c] * DD + k0 + lk),
          (__attribute__((address_space(3))) unsigned int*)(Bs + c * 2048 + w * 512),
          16, 0, 0);
    }
    __syncthreads();
    bf16x8 af[4], bfr[4];
#pragma unroll
    for (int i = 0; i < 4; i++) {
      af[i]  = *(const bf16x8*)&As[(wr + i * 16 + l15) * 32 + quad8];
      bfr[i] = *(const bf16x8*)&Bs[(wc + i * 16 + l15) * 32 + quad8];
    }
#pragma unroll
    for (int mi = 0; mi < 4; mi++)
#pragma unroll
      for (int ni = 0; ni < 4; ni++)
        acc[mi][ni] = __builtin_amdgcn_mfma_f32_16x16x32_bf16(af[mi], bfr[ni], acc[mi][ni], 0, 0, 0);
  }
#pragma unroll
  for (int ni = 0; ni < 4; ni++) {
    int col = wc + ni * 16 + l15;
    float bias = (col < 64) ? bcat[64 + m * 64 + col] : bcat[640 + m * 64 + (col - 64)];
#pragma unroll
    for (int mi = 0; mi < 4; mi++) {
      int ibase = wr + mi * 16 + quad * 4;
#pragma unroll
      for (int r = 0; r < 4; r++) {
        int pos = tile * 128 + ibase + r;
        float v = (pos < L) ? (acc[mi][ni][r] + bias) : 0.f;
        KVp[((size_t)seg * SEGCAP + pos) * 128 + col] = f2bf(v);
      }
    }
  }
}

// ---------------------------------------------------------------
// chunk_intra (packed): S^T = V^T K -> Sb16 ; O_intra = tril(QK^T)V
// ---------------------------------------------------------------
__global__ __launch_bounds__(256) void chunk_intra(
    const unsigned short* __restrict__ Qb, const unsigned short* __restrict__ KVp,
    const int* __restrict__ tlist, const float* __restrict__ alist,
    const int* __restrict__ seglen,
    unsigned short* __restrict__ Sb16, float* __restrict__ out) {
  const int chunk = blockIdx.x, seg = blockIdx.y;
  const int L = seglen[seg];
  const int t0 = chunk * CH;
  if (t0 >= L) return;
  __shared__ unsigned short Qs[64 * LDP];
  __shared__ unsigned short Ks[64 * LDP];
  __shared__ unsigned short KTs[64 * LDP];
  __shared__ unsigned short VTs[64 * LDP];
  const int b = seg / MP1;
  const int tid = threadIdx.x;
  const int* tl = tlist + (size_t)seg * SEGCAP;
  {
    int row = tid >> 2, c16 = (tid & 3) << 4;
    int pos = t0 + row;
    const unsigned short* kvb = KVp + ((size_t)seg * SEGCAP + pos) * 128;
    U8 k0, k1, v0, v1;
    k0.v = *(const uint4*)(kvb + c16);
    k1.v = *(const uint4*)(kvb + c16 + 8);
    v0.v = *(const uint4*)(kvb + 64 + c16);
    v1.v = *(const uint4*)(kvb + 64 + c16 + 8);
    *(uint4*)&Ks[row * LDP + c16]     = k0.v;
    *(uint4*)&Ks[row * LDP + c16 + 8] = k1.v;
#pragma unroll
    for (int j = 0; j < 8; j++) {
      KTs[(c16 + j) * LDP + row]     = k0.s[j];
      KTs[(c16 + 8 + j) * LDP + row] = k1.s[j];
      VTs[(c16 + j) * LDP + row]     = v0.s[j];
      VTs[(c16 + 8 + j) * LDP + row] = v1.s[j];
    }
    const unsigned short* qb = Qb + (size_t)(tl[pos] * BB + b) * HD;
    *(uint4*)&Qs[row * LDP + c16]     = *(const uint4*)(qb + c16);
    *(uint4*)&Qs[row * LDP + c16 + 8] = *(const uint4*)(qb + c16 + 8);
  }
  __syncthreads();
  const int lane = tid & 63, w = tid >> 6;
  const int quad = lane >> 4, l15 = lane & 15;
  {
    const unsigned short* arow = &VTs[(w * 16 + l15) * LDP];
    bf16x8 a0 = *(const bf16x8*)(arow + quad * 8);
    bf16x8 a1 = *(const bf16x8*)(arow + 32 + quad * 8);
    unsigned short* Sp = Sb16 + ((size_t)seg * NC + chunk) * 4096;
#pragma unroll
    for (int n = 0; n < 4; n++) {
      const unsigned short* brow = &KTs[(n * 16 + l15) * LDP];
      f32x4 acc = __builtin_amdgcn_mfma_f32_16x16x32_bf16(a0, *(const bf16x8*)(brow + quad * 8),
                                                          (f32x4){0.f,0.f,0.f,0.f}, 0, 0, 0);
      acc = __builtin_amdgcn_mfma_f32_16x16x32_bf16(a1, *(const bf16x8*)(brow + 32 + quad * 8),
                                                    acc, 0, 0, 0);
#pragma unroll
      for (int r = 0; r < 4; r++)
        Sp[(w * 16 + quad * 4 + r) * 64 + n * 16 + l15] = f2bf(acc[r]);
    }
  }
  unsigned short* qrow = &Qs[(w * 16 + l15) * LDP];
  bf16x8 aq0 = *(const bf16x8*)(qrow + quad * 8);
  bf16x8 aq1 = *(const bf16x8*)(qrow + 32 + quad * 8);
  f32x4 pp[4];
#pragma unroll
  for (int n = 0; n < 4; n++) {
    const unsigned short* krow = &Ks[(n * 16 + l15) * LDP];
    pp[n] = __builtin_amdgcn_mfma_f32_16x16x32_bf16(aq0, *(const bf16x8*)(krow + quad * 8),
                                                    (f32x4){0.f,0.f,0.f,0.f}, 0, 0, 0);
    pp[n] = __builtin_amdgcn_mfma_f32_16x16x32_bf16(aq1, *(const bf16x8*)(krow + 32 + quad * 8),
                                                    pp[n], 0, 0, 0);
  }
#pragma unroll
  for (int n = 0; n < 4; n++)
#pragma unroll
    for (int r = 0; r < 4; r++) {
      int i = w * 16 + quad * 4 + r, j = n * 16 + l15;
      Qs[i * LDP + j] = (j <= i) ? f2bf(pp[n][r]) : (unsigned short)0;
    }
  bf16x8 ap0 = *(const bf16x8*)(qrow + quad * 8);
  bf16x8 ap1 = *(const bf16x8*)(qrow + 32 + quad * 8);
  f32x4 po[4];
#pragma unroll
  for (int n = 0; n < 4; n++) {
    const unsigned short* vrow = &VTs[(n * 16 + l15) * LDP];
    po[n] = __builtin_amdgcn_mfma_f32_16x16x32_bf16(ap0, *(const bf16x8*)(vrow + quad * 8),
                                                    (f32x4){0.f,0.f,0.f,0.f}, 0, 0, 0);
    po[n] = __builtin_amdgcn_mfma_f32_16x16x32_bf16(ap1, *(const bf16x8*)(vrow + 32 + quad * 8),
                                                    po[n], 0, 0, 0);
  }
#pragma unroll
  for (int r = 0; r < 4; r++) {
    int pos = t0 + w * 16 + quad * 4 + r;
    if (pos < L) {
      int t = tl[pos];
      float alpha = alist[(size_t)seg * SEGCAP + pos];
#pragma unroll
      for (int n = 0; n < 4; n++)
        atomicAdd(&out[(size_t)(t * BB + b) * HD + n * 16 + l15], alpha * po[n][r]);
    }
  }
}

// ---------------------------------------------------------------
// scan: exclusive prefix over active chunks (bf16 in/out, fp32 carry)
// ---------------------------------------------------------------
__global__ __launch_bounds__(256) void scan_kernel(
    const float* __restrict__ M0, const int* __restrict__ seglen,
    unsigned short* __restrict__ Sb16) {
  const int seg = blockIdx.x >> 2, slab = blockIdx.x & 3;
  const int nch = (seglen[seg] + CH - 1) / CH;
  const int tid = threadIdx.x;
  const int off = slab * 1024 + tid * 4;
  float run[4];
#pragma unroll
  for (int u = 0; u < 4; u++) {
    int o = off + u;
    run[u] = M0[(o & 63) * 64 + (o >> 6)];   // M0^T
  }
  unsigned short* base = Sb16 + (size_t)seg * NC * 4096;
  for (int c = 0; c < nch; c++) {
    unsigned short* p = base + c * 4096 + off;
    ushort4 s = *(const ushort4*)p;
    ushort4 o;
    o.x = f2bf(run[0]); o.y = f2bf(run[1]); o.z = f2bf(run[2]); o.w = f2bf(run[3]);
    *(ushort4*)p = o;
    run[0] += bf2f(s.x); run[1] += bf2f(s.y); run[2] += bf2f(s.z); run[3] += bf2f(s.w);
  }
}

// ---------------------------------------------------------------
// chunk_inter (packed): O_inter = Q @ M_state ; alpha scatter
// ---------------------------------------------------------------
__global__ __launch_bounds__(256) void chunk_inter(
    const unsigned short* __restrict__ Qb, const unsigned short* __restrict__ Sb16,
    const int* __restrict__ tlist, const float* __restrict__ alist,
    const int* __restrict__ seglen, float* __restrict__ out) {
  const int chunk = blockIdx.x, seg = blockIdx.y;
  const int L = seglen[seg];
  const int t0 = chunk * CH;
  if (t0 >= L) return;
  __shared__ unsigned short Qs[64 * LDP];
  __shared__ unsigned short MT[64 * LDP];
  const int b = seg / MP1;
  const int tid = threadIdx.x;
  const int* tl = tlist + (size_t)seg * SEGCAP;
  {
    int row = tid >> 2, c16 = (tid & 3) << 4;
    int pos = t0 + row;
    const unsigned short* qb = Qb + (size_t)(tl[pos] * BB + b) * HD;
    *(uint4*)&Qs[row * LDP + c16]     = *(const uint4*)(qb + c16);
    *(uint4*)&Qs[row * LDP + c16 + 8] = *(const uint4*)(qb + c16 + 8);
    const unsigned short* Mp = Sb16 + ((size_t)seg * NC + chunk) * 4096 + row * 64 + c16;
    *(uint4*)&MT[row * LDP + c16]     = *(const uint4*)(Mp);
    *(uint4*)&MT[row * LDP + c16 + 8] = *(const uint4*)(Mp + 8);
  }
  __syncthreads();
  const int lane = tid & 63, w = tid >> 6;
  const int quad = lane >> 4, l15 = lane & 15;
  const unsigned short* qrow = &Qs[(w * 16 + l15) * LDP];
  bf16x8 aq0 = *(const bf16x8*)(qrow + quad * 8);
  bf16x8 aq1 = *(const bf16x8*)(qrow + 32 + quad * 8);
  f32x4 po[4];
#pragma unroll
  for (int n = 0; n < 4; n++) {
    const unsigned short* mrow = &MT[(n * 16 + l15) * LDP];
    po[n] = __builtin_amdgcn_mfma_f32_16x16x32_bf16(aq0, *(const bf16x8*)(mrow + quad * 8),
                                                    (f32x4){0.f,0.f,0.f,0.f}, 0, 0, 0);
    po[n] = __builtin_amdgcn_mfma_f32_16x16x32_bf16(aq1, *(const bf16x8*)(mrow + 32 + quad * 8),
                                                    po[n], 0, 0, 0);
  }
#pragma unroll
  for (int r = 0; r < 4; r++) {
    int pos = t0 + w * 16 + quad * 4 + r;
    if (pos < L) {
      int t = tl[pos];
      float alpha = alist[(size_t)seg * SEGCAP + pos];
#pragma unroll
      for (int n = 0; n < 4; n++)
        atomicAdd(&out[(size_t)(t * BB + b) * HD + n * 16 + l15], alpha * po[n][r]);
    }
  }
}

// ---------------------------------------------------------------
extern "C" void kernel_launch(void* const* d_in, const int* in_sizes, int n_in,
                              void* d_out, int out_size, void* d_ws, size_t ws_size,
                              hipStream_t stream) {
  const float* X  = (const float*)d_in[0];
  const float* M0 = (const float*)d_in[1];
  const float* Wq = (const float*)d_in[2];
  const float* bq = (const float*)d_in[3];
  const float* Wk = (const float*)d_in[4];
  const float* bk = (const float*)d_in[5];
  const float* Wv = (const float*)d_in[6];
  const float* bv = (const float*)d_in[7];
  const float* Wg = (const float*)d_in[8];
  const float* bg = (const float*)d_in[9];

  char* ws = (char*)d_ws;
  unsigned short* Xbf  = (unsigned short*)(ws);                  // 33,554,432
  unsigned short* Wt   = (unsigned short*)(ws + 33554432ULL);    //  2,621,440
  float*          bcat = (float*)         (ws + 36175872ULL);    //      5,120
  unsigned short* Qb   = (unsigned short*)(ws + 36184064ULL);    //  2,097,152
  unsigned short* KVp  = (unsigned short*)(ws + 38281216ULL);    // 37,748,736
  unsigned short* Sb16 = (unsigned short*)(ws + 76029952ULL);    // 18,874,368
  int2*           idxb = (int2*)          (ws + 94904320ULL);    //    131,072
  float2*         alfb = (float2*)        (ws + 95035392ULL);    //    131,072
  int*            tlist= (int*)           (ws + 95166464ULL);    //    589,824
  float*          alist= (float*)         (ws + 95756288ULL);    //    589,824
  int*            slen = (int*)           (ws + 96346112ULL);    //        288

  float* out = (float*)d_out;
  hipMemsetAsync(d_out, 0, (size_t)out_size * sizeof(float), stream);

  prep<<<320 + NTOK / 16, 256, 0, stream>>>(X, Wq, Wk, Wv, bq, bk, bv, Wg, bg,
                                            Wt, bcat, idxb, alfb, Xbf);
  pack_kernel<<<NSEG, 256, 0, stream>>>(idxb, alfb, tlist, alist, slen);
  proj_q<<<NTOK / 128, 256, 0, stream>>>(Xbf, Wt, bcat, Qb);
  proj_kv<<<dim3(16, NSEG), 256, 0, stream>>>(Xbf, Wt, bcat, tlist, slen, KVp);
  chunk_intra<<<dim3(NC, NSEG), 256, 0, stream>>>(Qb, KVp, tlist, alist, slen, Sb16, out);
  scan_kernel<<<NSEG * 4, 256, 0, stream>>>(M0, slen, Sb16);
  chunk_inter<<<dim3(NC, NSEG), 256, 0, stream>>>(Qb, Sb16, tlist, alist, slen, out);
}

// Round 9
// 255.750 us; speedup vs baseline: 1.0232x; 1.0232x over previous
//
#include <hip/hip_runtime.h>

#define TT   2048
#define BB   8
#define DD   1024
#define HD   64        // head dim d
#define MP1  9         // NM + 1
#define NTOK (TT*BB)   // 16384
#define CH   64        // chunk length
#define NC   32        // max chunks per segment
#define NSEG (BB*MP1)  // 72 segments
#define SEGCAP 2048    // max packed positions per segment
#define LDP  72        // padded LDS row stride (16B-aligned)
#define KVTILES 32     // per-seg BM=64 tiles
#define NKVB (KVTILES*NSEG)   // 2304

typedef __attribute__((ext_vector_type(8))) short bf16x8;
typedef __attribute__((ext_vector_type(4))) float f32x4;

union U8 { uint4 v; unsigned short s[8]; };

static __device__ __forceinline__ unsigned short f2bf(float f) {
  union { float f; unsigned u; } c; c.f = f;
  unsigned r = (c.u + 0x7FFF + ((c.u >> 16) & 1)) >> 16;   // RNE
  return (unsigned short)r;
}
static __device__ __forceinline__ float bf2f(unsigned short s) {
  union { unsigned u; float f; } c; c.u = ((unsigned)s) << 16;
  return c.f;
}

// ---------------------------------------------------------------
// prep: blocks [0,320) = weight transpose/cast; rest = gating
// ---------------------------------------------------------------
__global__ __launch_bounds__(256) void prep(
    const float* __restrict__ X,
    const float* __restrict__ Wq, const float* __restrict__ Wk,
    const float* __restrict__ Wv, const float* __restrict__ bq,
    const float* __restrict__ bk, const float* __restrict__ bv,
    const float* __restrict__ Wg, const float* __restrict__ bg,
    unsigned short* __restrict__ Wt, float* __restrict__ bcat,
    int2* __restrict__ idxb, float2* __restrict__ alfb,
    unsigned short* __restrict__ Xbf) {
  __shared__ float smem[8 * DD];
  const int tid = threadIdx.x;
  const int id = blockIdx.x;
  if (id < 320) {
    float (*tile)[65] = (float(*)[65])smem;
    const int n0 = (id % 20) * 64, k0 = (id / 20) * 64;
    const int c = tid & 63, rr = tid >> 6;
#pragma unroll 4
    for (int i = 0; i < 16; i++) {
      int kk = k0 + rr * 16 + i;
      int n  = n0 + c;
      float v = 0.f;
      if (n0 < 64)        v = Wq[kk * 64 + n];
      else if (n0 < 640)  v = Wk[kk * 576 + (n - 64)];
      else if (n0 < 1216) v = Wv[kk * 576 + (n - 640)];
      tile[rr * 16 + i][c] = v;
    }
    __syncthreads();
    const int lk = (tid & 15) * 4, ln = tid >> 4;
#pragma unroll
    for (int p = 0; p < 4; p++) {
      int nl = p * 16 + ln;
      ushort4 o;
      o.x = f2bf(tile[lk + 0][nl]); o.y = f2bf(tile[lk + 1][nl]);
      o.z = f2bf(tile[lk + 2][nl]); o.w = f2bf(tile[lk + 3][nl]);
      *(ushort4*)&Wt[(size_t)(n0 + nl) * DD + k0 + lk] = o;
    }
    if (id == 0) {
      for (int idx = tid; idx < 1280; idx += 256) {
        float b = 0.f;
        if (idx < 64)        b = bq[idx];
        else if (idx < 640)  b = bk[idx - 64];
        else if (idx < 1216) b = bv[idx - 640];
        bcat[idx] = b;
      }
    }
    return;
  }
  float* wgT = smem;
  for (int idx = tid; idx < 8 * DD; idx += 256) {
    int i = idx >> 3, j = idx & 7;
    wgT[j * DD + i] = Wg[idx];
  }
  __syncthreads();
  const int lane = tid & 63, wave = tid >> 6;
  const int base_tok = (id - 320) * 16 + wave * 4;
  for (int tk = 0; tk < 4; tk++) {
    const int tok = base_tok + tk;
    const float* xr = X + (size_t)tok * DD;
    unsigned short* xbr = Xbf + (size_t)tok * DD;
    float p[8] = {0.f,0.f,0.f,0.f,0.f,0.f,0.f,0.f};
#pragma unroll
    for (int it = 0; it < 4; it++) {
      int i = it * 256 + lane * 4;
      float4 x = *(const float4*)&xr[i];
      ushort4 o;
      o.x = f2bf(x.x); o.y = f2bf(x.y); o.z = f2bf(x.z); o.w = f2bf(x.w);
      *(ushort4*)&xbr[i] = o;
#pragma unroll
      for (int j = 0; j < 8; j++) {
        float4 wv = *(const float4*)&wgT[j * DD + i];
        p[j] += x.x * wv.x + x.y * wv.y + x.z * wv.z + x.w * wv.w;
      }
    }
#pragma unroll
    for (int j = 0; j < 8; j++) {
      float v = p[j];
#pragma unroll
      for (int off = 32; off > 0; off >>= 1) v += __shfl_xor(v, off);
      p[j] = v + bg[j];
    }
    if (lane == 0) {
      int i1 = 0; float z1 = p[0];
#pragma unroll
      for (int j = 1; j < 8; j++) if (p[j] > z1) { z1 = p[j]; i1 = j; }
      int i2 = -1; float z2 = -3.0e38f;
#pragma unroll
      for (int j = 0; j < 8; j++) if (j != i1 && p[j] > z2) { z2 = p[j]; i2 = j; }
      float e   = expf(z2 - z1);
      float inv = 1.0f / (1.0f + e);
      idxb[tok] = make_int2(i1 + 1, i2 + 1);
      alfb[tok] = make_float2(inv, e * inv);
    }
  }
}

// ---------------------------------------------------------------
// pack: per segment (b,m), time-ordered routed token list via
// wave ballot + 4-entry cross-wave scan (few barriers)
// ---------------------------------------------------------------
__global__ __launch_bounds__(256) void pack_kernel(
    const int2* __restrict__ idxb, const float2* __restrict__ alfb,
    int* __restrict__ tlist, float* __restrict__ alist,
    int* __restrict__ seglen) {
  const int seg = blockIdx.x;
  const int b = seg / MP1, m = seg % MP1;
  const int tid = threadIdx.x;
  int* tl = tlist + (size_t)seg * SEGCAP;
  float* al = alist + (size_t)seg * SEGCAP;
  if (m == 0) {
    for (int pos = tid; pos < TT; pos += 256) { tl[pos] = pos; al[pos] = 1.f; }
    if (tid == 0) seglen[seg] = TT;
    return;
  }
  __shared__ int wsum[4];
  const int lane = tid & 63, w = tid >> 6;
  int base = 0;
  for (int r = 0; r < TT / 256; r++) {
    int t = r * 256 + tid;
    int2 ix = idxb[t * BB + b];
    bool f = (ix.x == m || ix.y == m);
    float2 af = alfb[t * BB + b];
    float alpha = (ix.x == m) ? af.x : af.y;
    unsigned long long mask = __ballot(f);
    int lanepos = __popcll(mask & ((1ull << lane) - 1ull));
    if (lane == 0) wsum[w] = __popcll(mask);
    __syncthreads();
    int wbase = 0, total = 0;
#pragma unroll
    for (int i = 0; i < 4; i++) { int v = wsum[i]; if (i < w) wbase += v; total += v; }
    if (f) { int pos = base + wbase + lanepos; tl[pos] = t; al[pos] = alpha; }
    base += total;
    __syncthreads();
  }
  if (tid == 0) seglen[seg] = base;
  int Lpad = (base + 63) & ~63;
  for (int pos = base + tid; pos < Lpad; pos += 256) { tl[pos] = 0; al[pos] = 0.f; }
}

// ---------------------------------------------------------------
// proj_qkv: one dispatch, two paths.
//  bid < NKVB : gathered KV GEMM, BM=64 x BN=128 per (seg, tile)
//  bid >= NKVB: dense Q GEMM, BM=128 x BN=64
// ---------------------------------------------------------------
__global__ __launch_bounds__(256) void proj_qkv(
    const unsigned short* __restrict__ Xbf, const unsigned short* __restrict__ Wt,
    const float* __restrict__ bcat, const int* __restrict__ tlist,
    const int* __restrict__ seglen,
    unsigned short* __restrict__ Qb, unsigned short* __restrict__ KVp) {
  __shared__ unsigned short sm[6144];   // 12 KB, both paths
  const int bid = blockIdx.x;
  const int tid = threadIdx.x;
  const int lane = tid & 63, w = tid >> 6;
  const int lrow = lane >> 2, lk = (lane & 3) * 8;
  const int l15 = lane & 15, quad = lane >> 4, quad8 = quad * 8;

  if (bid < NKVB) {
    const int tile = bid & (KVTILES - 1), seg = bid >> 5;
    const int L = seglen[seg];
    if (tile * 64 >= L) return;
    const int b = seg / MP1, m = seg % MP1;
    unsigned short* As = sm;            // 64 x 32
    unsigned short* Bs = sm + 2048;     // 128 x 32
    const int* tl = tlist + (size_t)seg * SEGCAP;
    const int srcrow = tl[tile * 64 + w * 16 + lrow] * BB + b;
    int nrow[2];
#pragma unroll
    for (int c = 0; c < 2; c++) {
      int rr = c * 64 + w * 16 + lrow;
      nrow[c] = (rr < 64) ? (64 + m * 64 + rr) : (640 + m * 64 + (rr - 64));
    }
    const int wr = (w & 1) * 32, wc = (w >> 1) * 64;
    f32x4 acc[2][4];
#pragma unroll
    for (int i = 0; i < 2; i++)
#pragma unroll
      for (int j = 0; j < 4; j++) acc[i][j] = (f32x4){0.f,0.f,0.f,0.f};
    for (int k0 = 0; k0 < DD; k0 += 32) {
      __syncthreads();
      __builtin_amdgcn_global_load_lds(
          (const __attribute__((address_space(1))) unsigned int*)(Xbf + (size_t)srcrow * DD + k0 + lk),
          (__attribute__((address_space(3))) unsigned int*)(As + w * 512), 16, 0, 0);
#pragma unroll
      for (int c = 0; c < 2; c++)
        __builtin_amdgcn_global_load_lds(
            (const __attribute__((address_space(1))) unsigned int*)(Wt + (size_t)nrow[c] * DD + k0 + lk),
            (__attribute__((address_space(3))) unsigned int*)(Bs + c * 2048 + w * 512), 16, 0, 0);
      __syncthreads();
      bf16x8 af[2], bfr[4];
#pragma unroll
      for (int i = 0; i < 2; i++)
        af[i] = *(const bf16x8*)&As[(wr + i * 16 + l15) * 32 + quad8];
#pragma unroll
      for (int j = 0; j < 4; j++)
        bfr[j] = *(const bf16x8*)&Bs[(wc + j * 16 + l15) * 32 + quad8];
#pragma unroll
      for (int mi = 0; mi < 2; mi++)
#pragma unroll
        for (int ni = 0; ni < 4; ni++)
          acc[mi][ni] = __builtin_amdgcn_mfma_f32_16x16x32_bf16(af[mi], bfr[ni], acc[mi][ni], 0, 0, 0);
    }
#pragma unroll
    for (int ni = 0; ni < 4; ni++) {
      int col = wc + ni * 16 + l15;
      float bias = (col < 64) ? bcat[64 + m * 64 + col] : bcat[640 + m * 64 + (col - 64)];
#pragma unroll
      for (int mi = 0; mi < 2; mi++) {
#pragma unroll
        for (int r = 0; r < 4; r++) {
          int pos = tile * 64 + wr + mi * 16 + quad * 4 + r;
          float v = (pos < L) ? (acc[mi][ni][r] + bias) : 0.f;
          KVp[((size_t)seg * SEGCAP + pos) * 128 + col] = f2bf(v);
        }
      }
    }
    return;
  }
  // ---- dense Q path: BM=128, BN=64 ----
  const int row0 = (bid - NKVB) * 128;
  unsigned short* As = sm;            // 128 x 32
  unsigned short* Bs = sm + 4096;     // 64 x 32
  f32x4 acc[2][4];
#pragma unroll
  for (int i = 0; i < 2; i++)
#pragma unroll
    for (int j = 0; j < 4; j++) acc[i][j] = (f32x4){0.f,0.f,0.f,0.f};
  for (int k0 = 0; k0 < DD; k0 += 32) {
    __syncthreads();
#pragma unroll
    for (int c = 0; c < 2; c++) {
      int r = w * 32 + c * 16 + lrow;
      __builtin_amdgcn_global_load_lds(
          (const __attribute__((address_space(1))) unsigned int*)(Xbf + (size_t)(row0 + r) * DD + k0 + lk),
          (__attribute__((address_space(3))) unsigned int*)(As + (w * 32 + c * 16) * 32), 16, 0, 0);
    }
    __builtin_amdgcn_global_load_lds(
        (const __attribute__((address_space(1))) unsigned int*)(Wt + (size_t)(w * 16 + lrow) * DD + k0 + lk),
        (__attribute__((address_space(3))) unsigned int*)(Bs + w * 512), 16, 0, 0);
    __syncthreads();
    bf16x8 af[2], bfr[4];
#pragma unroll
    for (int i = 0; i < 2; i++)
      af[i] = *(const bf16x8*)&As[(w * 32 + i * 16 + l15) * 32 + quad8];
#pragma unroll
    for (int j = 0; j < 4; j++)
      bfr[j] = *(const bf16x8*)&Bs[(j * 16 + l15) * 32 + quad8];
#pragma unroll
    for (int mi = 0; mi < 2; mi++)
#pragma unroll
      for (int ni = 0; ni < 4; ni++)
        acc[mi][ni] = __builtin_amdgcn_mfma_f32_16x16x32_bf16(af[mi], bfr[ni], acc[mi][ni], 0, 0, 0);
  }
#pragma unroll
  for (int ni = 0; ni < 4; ni++) {
    int col = ni * 16 + l15;
    float bias = bcat[col];
#pragma unroll
    for (int mi = 0; mi < 2; mi++) {
      int rbase = row0 + w * 32 + mi * 16 + quad * 4;
#pragma unroll
      for (int r = 0; r < 4; r++)
        Qb[(size_t)(rbase + r) * HD + col] = f2bf(acc[mi][ni][r] + bias);
    }
  }
}

// ---------------------------------------------------------------
// chunk_intra (packed): S^T = V^T K -> Sb16 ; O_intra = tril(QK^T)V
// ---------------------------------------------------------------
__global__ __launch_bounds__(256) void chunk_intra(
    const unsigned short* __restrict__ Qb, const unsigned short* __restrict__ KVp,
    const int* __restrict__ tlist, const float* __restrict__ alist,
    const int* __restrict__ seglen,
    unsigned short* __restrict__ Sb16, float* __restrict__ out) {
  const int chunk = blockIdx.x, seg = blockIdx.y;
  const int L = seglen[seg];
  const int t0 = chunk * CH;
  if (t0 >= L) return;
  __shared__ unsigned short Qs[64 * LDP];
  __shared__ unsigned short Ks[64 * LDP];
  __shared__ unsigned short KTs[64 * LDP];
  __shared__ unsigned short VTs[64 * LDP];
  const int b = seg / MP1;
  const int tid = threadIdx.x;
  const int* tl = tlist + (size_t)seg * SEGCAP;
  {
    int row = tid >> 2, c16 = (tid & 3) << 4;
    int pos = t0 + row;
    const unsigned short* kvb = KVp + ((size_t)seg * SEGCAP + pos) * 128;
    U8 k0, k1, v0, v1;
    k0.v = *(const uint4*)(kvb + c16);
    k1.v = *(const uint4*)(kvb + c16 + 8);
    v0.v = *(const uint4*)(kvb + 64 + c16);
    v1.v = *(const uint4*)(kvb + 64 + c16 + 8);
    *(uint4*)&Ks[row * LDP + c16]     = k0.v;
    *(uint4*)&Ks[row * LDP + c16 + 8] = k1.v;
#pragma unroll
    for (int j = 0; j < 8; j++) {
      KTs[(c16 + j) * LDP + row]     = k0.s[j];
      KTs[(c16 + 8 + j) * LDP + row] = k1.s[j];
      VTs[(c16 + j) * LDP + row]     = v0.s[j];
      VTs[(c16 + 8 + j) * LDP + row] = v1.s[j];
    }
    const unsigned short* qb = Qb + (size_t)(tl[pos] * BB + b) * HD;
    *(uint4*)&Qs[row * LDP + c16]     = *(const uint4*)(qb + c16);
    *(uint4*)&Qs[row * LDP + c16 + 8] = *(const uint4*)(qb + c16 + 8);
  }
  __syncthreads();
  const int lane = tid & 63, w = tid >> 6;
  const int quad = lane >> 4, l15 = lane & 15;
  {
    const unsigned short* arow = &VTs[(w * 16 + l15) * LDP];
    bf16x8 a0 = *(const bf16x8*)(arow + quad * 8);
    bf16x8 a1 = *(const bf16x8*)(arow + 32 + quad * 8);
    unsigned short* Sp = Sb16 + ((size_t)seg * NC + chunk) * 4096;
#pragma unroll
    for (int n = 0; n < 4; n++) {
      const unsigned short* brow = &KTs[(n * 16 + l15) * LDP];
      f32x4 acc = __builtin_amdgcn_mfma_f32_16x16x32_bf16(a0, *(const bf16x8*)(brow + quad * 8),
                                                          (f32x4){0.f,0.f,0.f,0.f}, 0, 0, 0);
      acc = __builtin_amdgcn_mfma_f32_16x16x32_bf16(a1, *(const bf16x8*)(brow + 32 + quad * 8),
                                                    acc, 0, 0, 0);
#pragma unroll
      for (int r = 0; r < 4; r++)
        Sp[(w * 16 + quad * 4 + r) * 64 + n * 16 + l15] = f2bf(acc[r]);
    }
  }
  unsigned short* qrow = &Qs[(w * 16 + l15) * LDP];
  bf16x8 aq0 = *(const bf16x8*)(qrow + quad * 8);
  bf16x8 aq1 = *(const bf16x8*)(qrow + 32 + quad * 8);
  f32x4 pp[4];
#pragma unroll
  for (int n = 0; n < 4; n++) {
    const unsigned short* krow = &Ks[(n * 16 + l15) * LDP];
    pp[n] = __builtin_amdgcn_mfma_f32_16x16x32_bf16(aq0, *(const bf16x8*)(krow + quad * 8),
                                                    (f32x4){0.f,0.f,0.f,0.f}, 0, 0, 0);
    pp[n] = __builtin_amdgcn_mfma_f32_16x16x32_bf16(aq1, *(const bf16x8*)(krow + 32 + quad * 8),
                                                    pp[n], 0, 0, 0);
  }
#pragma unroll
  for (int n = 0; n < 4; n++)
#pragma unroll
    for (int r = 0; r < 4; r++) {
      int i = w * 16 + quad * 4 + r, j = n * 16 + l15;
      Qs[i * LDP + j] = (j <= i) ? f2bf(pp[n][r]) : (unsigned short)0;
    }
  bf16x8 ap0 = *(const bf16x8*)(qrow + quad * 8);
  bf16x8 ap1 = *(const bf16x8*)(qrow + 32 + quad * 8);
  f32x4 po[4];
#pragma unroll
  for (int n = 0; n < 4; n++) {
    const unsigned short* vrow = &VTs[(n * 16 + l15) * LDP];
    po[n] = __builtin_amdgcn_mfma_f32_16x16x32_bf16(ap0, *(const bf16x8*)(vrow + quad * 8),
                                                    (f32x4){0.f,0.f,0.f,0.f}, 0, 0, 0);
    po[n] = __builtin_amdgcn_mfma_f32_16x16x32_bf16(ap1, *(const bf16x8*)(vrow + 32 + quad * 8),
                                                    po[n], 0, 0, 0);
  }
#pragma unroll
  for (int r = 0; r < 4; r++) {
    int pos = t0 + w * 16 + quad * 4 + r;
    if (pos < L) {
      int t = tl[pos];
      float alpha = alist[(size_t)seg * SEGCAP + pos];
#pragma unroll
      for (int n = 0; n < 4; n++)
        atomicAdd(&out[(size_t)(t * BB + b) * HD + n * 16 + l15], alpha * po[n][r]);
    }
  }
}

// ---------------------------------------------------------------
// scan: exclusive prefix over active chunks (bf16 in/out, fp32 carry)
// ---------------------------------------------------------------
__global__ __launch_bounds__(256) void scan_kernel(
    const float* __restrict__ M0, const int* __restrict__ seglen,
    unsigned short* __restrict__ Sb16) {
  const int seg = blockIdx.x >> 2, slab = blockIdx.x & 3;
  const int nch = (seglen[seg] + CH - 1) / CH;
  const int tid = threadIdx.x;
  const int off = slab * 1024 + tid * 4;
  float run[4];
#pragma unroll
  for (int u = 0; u < 4; u++) {
    int o = off + u;
    run[u] = M0[(o & 63) * 64 + (o >> 6)];   // M0^T
  }
  unsigned short* base = Sb16 + (size_t)seg * NC * 4096;
  for (int c = 0; c < nch; c++) {
    unsigned short* p = base + c * 4096 + off;
    ushort4 s = *(const ushort4*)p;
    ushort4 o;
    o.x = f2bf(run[0]); o.y = f2bf(run[1]); o.z = f2bf(run[2]); o.w = f2bf(run[3]);
    *(ushort4*)p = o;
    run[0] += bf2f(s.x); run[1] += bf2f(s.y); run[2] += bf2f(s.z); run[3] += bf2f(s.w);
  }
}

// ---------------------------------------------------------------
// chunk_inter (packed): O_inter = Q @ M_state ; alpha scatter
// ---------------------------------------------------------------
__global__ __launch_bounds__(256) void chunk_inter(
    const unsigned short* __restrict__ Qb, const unsigned short* __restrict__ Sb16,
    const int* __restrict__ tlist, const float* __restrict__ alist,
    const int* __restrict__ seglen, float* __restrict__ out) {
  const int chunk = blockIdx.x, seg = blockIdx.y;
  const int L = seglen[seg];
  const int t0 = chunk * CH;
  if (t0 >= L) return;
  __shared__ unsigned short Qs[64 * LDP];
  __shared__ unsigned short MT[64 * LDP];
  const int b = seg / MP1;
  const int tid = threadIdx.x;
  const int* tl = tlist + (size_t)seg * SEGCAP;
  {
    int row = tid >> 2, c16 = (tid & 3) << 4;
    int pos = t0 + row;
    const unsigned short* qb = Qb + (size_t)(tl[pos] * BB + b) * HD;
    *(uint4*)&Qs[row * LDP + c16]     = *(const uint4*)(qb + c16);
    *(uint4*)&Qs[row * LDP + c16 + 8] = *(const uint4*)(qb + c16 + 8);
    const unsigned short* Mp = Sb16 + ((size_t)seg * NC + chunk) * 4096 + row * 64 + c16;
    *(uint4*)&MT[row * LDP + c16]     = *(const uint4*)(Mp);
    *(uint4*)&MT[row * LDP + c16 + 8] = *(const uint4*)(Mp + 8);
  }
  __syncthreads();
  const int lane = tid & 63, w = tid >> 6;
  const int quad = lane >> 4, l15 = lane & 15;
  const unsigned short* qrow = &Qs[(w * 16 + l15) * LDP];
  bf16x8 aq0 = *(const bf16x8*)(qrow + quad * 8);
  bf16x8 aq1 = *(const bf16x8*)(qrow + 32 + quad * 8);
  f32x4 po[4];
#pragma unroll
  for (int n = 0; n < 4; n++) {
    const unsigned short* mrow = &MT[(n * 16 + l15) * LDP];
    po[n] = __builtin_amdgcn_mfma_f32_16x16x32_bf16(aq0, *(const bf16x8*)(mrow + quad * 8),
                                                    (f32x4){0.f,0.f,0.f,0.f}, 0, 0, 0);
    po[n] = __builtin_amdgcn_mfma_f32_16x16x32_bf16(aq1, *(const bf16x8*)(mrow + 32 + quad * 8),
                                                    po[n], 0, 0, 0);
  }
#pragma unroll
  for (int r = 0; r < 4; r++) {
    int pos = t0 + w * 16 + quad * 4 + r;
    if (pos < L) {
      int t = tl[pos];
      float alpha = alist[(size_t)seg * SEGCAP + pos];
#pragma unroll
      for (int n = 0; n < 4; n++)
        atomicAdd(&out[(size_t)(t * BB + b) * HD + n * 16 + l15], alpha * po[n][r]);
    }
  }
}

// ---------------------------------------------------------------
extern "C" void kernel_launch(void* const* d_in, const int* in_sizes, int n_in,
                              void* d_out, int out_size, void* d_ws, size_t ws_size,
                              hipStream_t stream) {
  const float* X  = (const float*)d_in[0];
  const float* M0 = (const float*)d_in[1];
  const float* Wq = (const float*)d_in[2];
  const float* bq = (const float*)d_in[3];
  const float* Wk = (const float*)d_in[4];
  const float* bk = (const float*)d_in[5];
  const float* Wv = (const float*)d_in[6];
  const float* bv = (const float*)d_in[7];
  const float* Wg = (const float*)d_in[8];
  const float* bg = (const float*)d_in[9];

  char* ws = (char*)d_ws;
  unsigned short* Xbf  = (unsigned short*)(ws);                  // 33,554,432
  unsigned short* Wt   = (unsigned short*)(ws + 33554432ULL);    //  2,621,440
  float*          bcat = (float*)         (ws + 36175872ULL);    //      5,120
  unsigned short* Qb   = (unsigned short*)(ws + 36184064ULL);    //  2,097,152
  unsigned short* KVp  = (unsigned short*)(ws + 38281216ULL);    // 37,748,736
  unsigned short* Sb16 = (unsigned short*)(ws + 76029952ULL);    // 18,874,368
  int2*           idxb = (int2*)          (ws + 94904320ULL);    //    131,072
  float2*         alfb = (float2*)        (ws + 95035392ULL);    //    131,072
  int*            tlist= (int*)           (ws + 95166464ULL);    //    589,824
  float*          alist= (float*)         (ws + 95756288ULL);    //    589,824
  int*            slen = (int*)           (ws + 96346112ULL);    //        288

  float* out = (float*)d_out;
  hipMemsetAsync(d_out, 0, (size_t)out_size * sizeof(float), stream);

  prep<<<320 + NTOK / 16, 256, 0, stream>>>(X, Wq, Wk, Wv, bq, bk, bv, Wg, bg,
                                            Wt, bcat, idxb, alfb, Xbf);
  pack_kernel<<<NSEG, 256, 0, stream>>>(idxb, alfb, tlist, alist, slen);
  proj_qkv<<<NKVB + NTOK / 128, 256, 0, stream>>>(Xbf, Wt, bcat, tlist, slen, Qb, KVp);
  chunk_intra<<<dim3(NC, NSEG), 256, 0, stream>>>(Qb, KVp, tlist, alist, slen, Sb16, out);
  scan_kernel<<<NSEG * 4, 256, 0, stream>>>(M0, slen, Sb16);
  chunk_inter<<<dim3(NC, NSEG), 256, 0, stream>>>(Qb, Sb16, tlist, alist, slen, out);
}

// Round 10
// 241.708 us; speedup vs baseline: 1.0827x; 1.0581x over previous
//
#include <hip/hip_runtime.h>

#define TT   2048
#define BB   8
#define DD   1024
#define HD   64        // head dim d
#define MP1  9         // NM + 1
#define NTOK (TT*BB)   // 16384
#define CH   64        // chunk length
#define NC   32        // max chunks per segment
#define NSEG (BB*MP1)  // 72 segments
#define SEGCAP 2048    // max packed positions per segment
#define NCAT 1280      // 64 Q + 576 K + 576 V + 64 pad
#define LDP  72        // padded LDS row stride (16B-aligned)

typedef __attribute__((ext_vector_type(8))) short bf16x8;
typedef __attribute__((ext_vector_type(4))) float f32x4;

union U8 { uint4 v; unsigned short s[8]; };

static __device__ __forceinline__ unsigned short f2bf(float f) {
  union { float f; unsigned u; } c; c.f = f;
  unsigned r = (c.u + 0x7FFF + ((c.u >> 16) & 1)) >> 16;   // RNE
  return (unsigned short)r;
}
static __device__ __forceinline__ float bf2f(unsigned short s) {
  union { unsigned u; float f; } c; c.u = ((unsigned)s) << 16;
  return c.f;
}

// ---------------------------------------------------------------
// prep: blocks [0,320) = weight transpose/cast; rest = gating
// ---------------------------------------------------------------
__global__ __launch_bounds__(256) void prep(
    const float* __restrict__ X,
    const float* __restrict__ Wq, const float* __restrict__ Wk,
    const float* __restrict__ Wv, const float* __restrict__ bq,
    const float* __restrict__ bk, const float* __restrict__ bv,
    const float* __restrict__ Wg, const float* __restrict__ bg,
    unsigned short* __restrict__ Wt, float* __restrict__ bcat,
    int2* __restrict__ idxb, float2* __restrict__ alfb,
    unsigned short* __restrict__ Xbf) {
  __shared__ float smem[8 * DD];
  const int tid = threadIdx.x;
  const int id = blockIdx.x;
  if (id < 320) {
    float (*tile)[65] = (float(*)[65])smem;
    const int n0 = (id % 20) * 64, k0 = (id / 20) * 64;
    const int c = tid & 63, rr = tid >> 6;
#pragma unroll 4
    for (int i = 0; i < 16; i++) {
      int kk = k0 + rr * 16 + i;
      int n  = n0 + c;
      float v = 0.f;
      if (n0 < 64)        v = Wq[kk * 64 + n];
      else if (n0 < 640)  v = Wk[kk * 576 + (n - 64)];
      else if (n0 < 1216) v = Wv[kk * 576 + (n - 640)];
      tile[rr * 16 + i][c] = v;
    }
    __syncthreads();
    const int lk = (tid & 15) * 4, ln = tid >> 4;
#pragma unroll
    for (int p = 0; p < 4; p++) {
      int nl = p * 16 + ln;
      ushort4 o;
      o.x = f2bf(tile[lk + 0][nl]); o.y = f2bf(tile[lk + 1][nl]);
      o.z = f2bf(tile[lk + 2][nl]); o.w = f2bf(tile[lk + 3][nl]);
      *(ushort4*)&Wt[(size_t)(n0 + nl) * DD + k0 + lk] = o;
    }
    if (id == 0) {
      for (int idx = tid; idx < NCAT; idx += 256) {
        float b = 0.f;
        if (idx < 64)        b = bq[idx];
        else if (idx < 640)  b = bk[idx - 64];
        else if (idx < 1216) b = bv[idx - 640];
        bcat[idx] = b;
      }
    }
    return;
  }
  float* wgT = smem;
  for (int idx = tid; idx < 8 * DD; idx += 256) {
    int i = idx >> 3, j = idx & 7;
    wgT[j * DD + i] = Wg[idx];
  }
  __syncthreads();
  const int lane = tid & 63, wave = tid >> 6;
  const int base_tok = (id - 320) * 16 + wave * 4;
  for (int tk = 0; tk < 4; tk++) {
    const int tok = base_tok + tk;
    const float* xr = X + (size_t)tok * DD;
    unsigned short* xbr = Xbf + (size_t)tok * DD;
    float p[8] = {0.f,0.f,0.f,0.f,0.f,0.f,0.f,0.f};
#pragma unroll
    for (int it = 0; it < 4; it++) {
      int i = it * 256 + lane * 4;
      float4 x = *(const float4*)&xr[i];
      ushort4 o;
      o.x = f2bf(x.x); o.y = f2bf(x.y); o.z = f2bf(x.z); o.w = f2bf(x.w);
      *(ushort4*)&xbr[i] = o;
#pragma unroll
      for (int j = 0; j < 8; j++) {
        float4 wv = *(const float4*)&wgT[j * DD + i];
        p[j] += x.x * wv.x + x.y * wv.y + x.z * wv.z + x.w * wv.w;
      }
    }
#pragma unroll
    for (int j = 0; j < 8; j++) {
      float v = p[j];
#pragma unroll
      for (int off = 32; off > 0; off >>= 1) v += __shfl_xor(v, off);
      p[j] = v + bg[j];
    }
    if (lane == 0) {
      int i1 = 0; float z1 = p[0];
#pragma unroll
      for (int j = 1; j < 8; j++) if (p[j] > z1) { z1 = p[j]; i1 = j; }
      int i2 = -1; float z2 = -3.0e38f;
#pragma unroll
      for (int j = 0; j < 8; j++) if (j != i1 && p[j] > z2) { z2 = p[j]; i2 = j; }
      float e   = expf(z2 - z1);
      float inv = 1.0f / (1.0f + e);
      idxb[tok] = make_int2(i1 + 1, i2 + 1);
      alfb[tok] = make_float2(inv, e * inv);
    }
  }
}

// ---------------------------------------------------------------
// pack: per segment (b,m), time-ordered routed token list via
// wave ballot + 4-entry cross-wave scan
// ---------------------------------------------------------------
__global__ __launch_bounds__(256) void pack_kernel(
    const int2* __restrict__ idxb, const float2* __restrict__ alfb,
    int* __restrict__ tlist, float* __restrict__ alist,
    int* __restrict__ seglen) {
  const int seg = blockIdx.x;
  const int b = seg / MP1, m = seg % MP1;
  const int tid = threadIdx.x;
  int* tl = tlist + (size_t)seg * SEGCAP;
  float* al = alist + (size_t)seg * SEGCAP;
  if (m == 0) {
    for (int pos = tid; pos < TT; pos += 256) { tl[pos] = pos; al[pos] = 1.f; }
    if (tid == 0) seglen[seg] = TT;
    return;
  }
  __shared__ int wsum[4];
  const int lane = tid & 63, w = tid >> 6;
  int base = 0;
  for (int r = 0; r < TT / 256; r++) {
    int t = r * 256 + tid;
    int2 ix = idxb[t * BB + b];
    bool f = (ix.x == m || ix.y == m);
    float2 af = alfb[t * BB + b];
    float alpha = (ix.x == m) ? af.x : af.y;
    unsigned long long mask = __ballot(f);
    int lanepos = __popcll(mask & ((1ull << lane) - 1ull));
    if (lane == 0) wsum[w] = __popcll(mask);
    __syncthreads();
    int wbase = 0, total = 0;
#pragma unroll
    for (int i = 0; i < 4; i++) { int v = wsum[i]; if (i < w) wbase += v; total += v; }
    if (f) { int pos = base + wbase + lanepos; tl[pos] = t; al[pos] = alpha; }
    base += total;
    __syncthreads();
  }
  if (tid == 0) seglen[seg] = base;
  int Lpad = (base + 63) & ~63;
  for (int pos = base + tid; pos < Lpad; pos += 256) { tl[pos] = 0; al[pos] = 0.f; }
}

// ---------------------------------------------------------------
// Dense projection GEMM (R7 known-good): (16384x1024)@(1024x1280)
// BM=BN=128; bx=row tile -> same-XCD row strip (L2-local X reuse)
// ---------------------------------------------------------------
__global__ __launch_bounds__(256) void proj_mfma(
    const unsigned short* __restrict__ Xbf, const unsigned short* __restrict__ Wt,
    const float* __restrict__ bcat, unsigned short* __restrict__ Ocat) {
  __shared__ unsigned short As[128 * 32];
  __shared__ unsigned short Bs[128 * 32];
  const int tid  = threadIdx.x;
  const int lane = tid & 63, w = tid >> 6;
  const int row0 = blockIdx.x * 128;
  const int col0 = blockIdx.y * 128;
  const int wr = (w >> 1) * 64, wc = (w & 1) * 64;
  const int lrow = lane >> 2;
  const int lk   = (lane & 3) * 8;

  f32x4 acc[4][4];
#pragma unroll
  for (int i = 0; i < 4; i++)
#pragma unroll
    for (int j = 0; j < 4; j++) acc[i][j] = (f32x4){0.f, 0.f, 0.f, 0.f};

  for (int k0 = 0; k0 < DD; k0 += 32) {
    __syncthreads();
#pragma unroll
    for (int c = 0; c < 2; c++) {
      int r = c * 64 + w * 16 + lrow;
      __builtin_amdgcn_global_load_lds(
          (const __attribute__((address_space(1))) unsigned int*)(Xbf + (size_t)(row0 + r) * DD + k0 + lk),
          (__attribute__((address_space(3))) unsigned int*)(As + c * 2048 + w * 512),
          16, 0, 0);
      __builtin_amdgcn_global_load_lds(
          (const __attribute__((address_space(1))) unsigned int*)(Wt + (size_t)(col0 + r) * DD + k0 + lk),
          (__attribute__((address_space(3))) unsigned int*)(Bs + c * 2048 + w * 512),
          16, 0, 0);
    }
    __syncthreads();
    bf16x8 af[4], bfr[4];
#pragma unroll
    for (int i = 0; i < 4; i++) {
      af[i]  = *(const bf16x8*)&As[(wr + i * 16 + (lane & 15)) * 32 + (lane >> 4) * 8];
      bfr[i] = *(const bf16x8*)&Bs[(wc + i * 16 + (lane & 15)) * 32 + (lane >> 4) * 8];
    }
#pragma unroll
    for (int mi = 0; mi < 4; mi++)
#pragma unroll
      for (int ni = 0; ni < 4; ni++)
        acc[mi][ni] = __builtin_amdgcn_mfma_f32_16x16x32_bf16(af[mi], bfr[ni], acc[mi][ni], 0, 0, 0);
  }
#pragma unroll
  for (int ni = 0; ni < 4; ni++) {
    int col = col0 + wc + ni * 16 + (lane & 15);
    float bias = bcat[col];
#pragma unroll
    for (int mi = 0; mi < 4; mi++) {
      int rbase = row0 + wr + mi * 16 + (lane >> 4) * 4;
#pragma unroll
      for (int r = 0; r < 4; r++) {
        float v = acc[mi][ni][r] + bias;
        Ocat[(size_t)(rbase + r) * NCAT + col] = f2bf(v);
      }
    }
  }
}

// ---------------------------------------------------------------
// chunk_intra (packed, gathered from Ocat):
// S^T = V^T K -> Sb16 ; O_intra = tril(QK^T) V ; alpha scatter
// pad positions (pos>=L): K zeroed -> no contribution anywhere
// ---------------------------------------------------------------
__global__ __launch_bounds__(256) void chunk_intra(
    const unsigned short* __restrict__ Ocat,
    const int* __restrict__ tlist, const float* __restrict__ alist,
    const int* __restrict__ seglen,
    unsigned short* __restrict__ Sb16, float* __restrict__ out) {
  const int chunk = blockIdx.x, seg = blockIdx.y;
  const int L = seglen[seg];
  const int t0 = chunk * CH;
  if (t0 >= L) return;
  __shared__ unsigned short Qs[64 * LDP];
  __shared__ unsigned short Ks[64 * LDP];
  __shared__ unsigned short KTs[64 * LDP];
  __shared__ unsigned short VTs[64 * LDP];
  const int b = seg / MP1, m = seg % MP1;
  const int tid = threadIdx.x;
  const int* tl = tlist + (size_t)seg * SEGCAP;
  {
    int row = tid >> 2, c16 = (tid & 3) << 4;
    int pos = t0 + row;
    int t = tl[pos];
    const unsigned short* obase = Ocat + (size_t)(t * BB + b) * NCAT;
    *(uint4*)&Qs[row * LDP + c16]     = *(const uint4*)(obase + c16);
    *(uint4*)&Qs[row * LDP + c16 + 8] = *(const uint4*)(obase + c16 + 8);
    U8 k0, k1, v0, v1;
    k0.v = *(const uint4*)(obase + 64 + m * 64 + c16);
    k1.v = *(const uint4*)(obase + 64 + m * 64 + c16 + 8);
    v0.v = *(const uint4*)(obase + 640 + m * 64 + c16);
    v1.v = *(const uint4*)(obase + 640 + m * 64 + c16 + 8);
    if (pos >= L) { uint4 z = {0,0,0,0}; k0.v = z; k1.v = z; }
    *(uint4*)&Ks[row * LDP + c16]     = k0.v;
    *(uint4*)&Ks[row * LDP + c16 + 8] = k1.v;
#pragma unroll
    for (int j = 0; j < 8; j++) {
      KTs[(c16 + j) * LDP + row]     = k0.s[j];
      KTs[(c16 + 8 + j) * LDP + row] = k1.s[j];
      VTs[(c16 + j) * LDP + row]     = v0.s[j];
      VTs[(c16 + 8 + j) * LDP + row] = v1.s[j];
    }
  }
  __syncthreads();
  const int lane = tid & 63, w = tid >> 6;
  const int quad = lane >> 4, l15 = lane & 15;
  {
    const unsigned short* arow = &VTs[(w * 16 + l15) * LDP];
    bf16x8 a0 = *(const bf16x8*)(arow + quad * 8);
    bf16x8 a1 = *(const bf16x8*)(arow + 32 + quad * 8);
    unsigned short* Sp = Sb16 + ((size_t)seg * NC + chunk) * 4096;
#pragma unroll
    for (int n = 0; n < 4; n++) {
      const unsigned short* brow = &KTs[(n * 16 + l15) * LDP];
      f32x4 acc = __builtin_amdgcn_mfma_f32_16x16x32_bf16(a0, *(const bf16x8*)(brow + quad * 8),
                                                          (f32x4){0.f,0.f,0.f,0.f}, 0, 0, 0);
      acc = __builtin_amdgcn_mfma_f32_16x16x32_bf16(a1, *(const bf16x8*)(brow + 32 + quad * 8),
                                                    acc, 0, 0, 0);
#pragma unroll
      for (int r = 0; r < 4; r++)
        Sp[(w * 16 + quad * 4 + r) * 64 + n * 16 + l15] = f2bf(acc[r]);
    }
  }
  unsigned short* qrow = &Qs[(w * 16 + l15) * LDP];
  bf16x8 aq0 = *(const bf16x8*)(qrow + quad * 8);
  bf16x8 aq1 = *(const bf16x8*)(qrow + 32 + quad * 8);
  f32x4 pp[4];
#pragma unroll
  for (int n = 0; n < 4; n++) {
    const unsigned short* krow = &Ks[(n * 16 + l15) * LDP];
    pp[n] = __builtin_amdgcn_mfma_f32_16x16x32_bf16(aq0, *(const bf16x8*)(krow + quad * 8),
                                                    (f32x4){0.f,0.f,0.f,0.f}, 0, 0, 0);
    pp[n] = __builtin_amdgcn_mfma_f32_16x16x32_bf16(aq1, *(const bf16x8*)(krow + 32 + quad * 8),
                                                    pp[n], 0, 0, 0);
  }
#pragma unroll
  for (int n = 0; n < 4; n++)
#pragma unroll
    for (int r = 0; r < 4; r++) {
      int i = w * 16 + quad * 4 + r, j = n * 16 + l15;
      Qs[i * LDP + j] = (j <= i) ? f2bf(pp[n][r]) : (unsigned short)0;
    }
  bf16x8 ap0 = *(const bf16x8*)(qrow + quad * 8);
  bf16x8 ap1 = *(const bf16x8*)(qrow + 32 + quad * 8);
  f32x4 po[4];
#pragma unroll
  for (int n = 0; n < 4; n++) {
    const unsigned short* vrow = &VTs[(n * 16 + l15) * LDP];
    po[n] = __builtin_amdgcn_mfma_f32_16x16x32_bf16(ap0, *(const bf16x8*)(vrow + quad * 8),
                                                    (f32x4){0.f,0.f,0.f,0.f}, 0, 0, 0);
    po[n] = __builtin_amdgcn_mfma_f32_16x16x32_bf16(ap1, *(const bf16x8*)(vrow + 32 + quad * 8),
                                                    po[n], 0, 0, 0);
  }
#pragma unroll
  for (int r = 0; r < 4; r++) {
    int pos = t0 + w * 16 + quad * 4 + r;
    if (pos < L) {
      int t = tl[pos];
      float alpha = alist[(size_t)seg * SEGCAP + pos];
#pragma unroll
      for (int n = 0; n < 4; n++)
        atomicAdd(&out[(size_t)(t * BB + b) * HD + n * 16 + l15], alpha * po[n][r]);
    }
  }
}

// ---------------------------------------------------------------
// scan: exclusive prefix over active chunks (bf16 in/out, fp32 carry)
// ---------------------------------------------------------------
__global__ __launch_bounds__(256) void scan_kernel(
    const float* __restrict__ M0, const int* __restrict__ seglen,
    unsigned short* __restrict__ Sb16) {
  const int seg = blockIdx.x >> 2, slab = blockIdx.x & 3;
  const int nch = (seglen[seg] + CH - 1) / CH;
  const int tid = threadIdx.x;
  const int off = slab * 1024 + tid * 4;
  float run[4];
#pragma unroll
  for (int u = 0; u < 4; u++) {
    int o = off + u;
    run[u] = M0[(o & 63) * 64 + (o >> 6)];   // M0^T
  }
  unsigned short* base = Sb16 + (size_t)seg * NC * 4096;
  for (int c = 0; c < nch; c++) {
    unsigned short* p = base + c * 4096 + off;
    ushort4 s = *(const ushort4*)p;
    ushort4 o;
    o.x = f2bf(run[0]); o.y = f2bf(run[1]); o.z = f2bf(run[2]); o.w = f2bf(run[3]);
    *(ushort4*)p = o;
    run[0] += bf2f(s.x); run[1] += bf2f(s.y); run[2] += bf2f(s.z); run[3] += bf2f(s.w);
  }
}

// ---------------------------------------------------------------
// chunk_inter (packed, gathered from Ocat): O = Q @ M_state
// ---------------------------------------------------------------
__global__ __launch_bounds__(256) void chunk_inter(
    const unsigned short* __restrict__ Ocat, const unsigned short* __restrict__ Sb16,
    const int* __restrict__ tlist, const float* __restrict__ alist,
    const int* __restrict__ seglen, float* __restrict__ out) {
  const int chunk = blockIdx.x, seg = blockIdx.y;
  const int L = seglen[seg];
  const int t0 = chunk * CH;
  if (t0 >= L) return;
  __shared__ unsigned short Qs[64 * LDP];
  __shared__ unsigned short MT[64 * LDP];
  const int b = seg / MP1;
  const int tid = threadIdx.x;
  const int* tl = tlist + (size_t)seg * SEGCAP;
  {
    int row = tid >> 2, c16 = (tid & 3) << 4;
    int pos = t0 + row;
    const unsigned short* qb = Ocat + (size_t)(tl[pos] * BB + b) * NCAT;
    *(uint4*)&Qs[row * LDP + c16]     = *(const uint4*)(qb + c16);
    *(uint4*)&Qs[row * LDP + c16 + 8] = *(const uint4*)(qb + c16 + 8);
    const unsigned short* Mp = Sb16 + ((size_t)seg * NC + chunk) * 4096 + row * 64 + c16;
    *(uint4*)&MT[row * LDP + c16]     = *(const uint4*)(Mp);
    *(uint4*)&MT[row * LDP + c16 + 8] = *(const uint4*)(Mp + 8);
  }
  __syncthreads();
  const int lane = tid & 63, w = tid >> 6;
  const int quad = lane >> 4, l15 = lane & 15;
  const unsigned short* qrow = &Qs[(w * 16 + l15) * LDP];
  bf16x8 aq0 = *(const bf16x8*)(qrow + quad * 8);
  bf16x8 aq1 = *(const bf16x8*)(qrow + 32 + quad * 8);
  f32x4 po[4];
#pragma unroll
  for (int n = 0; n < 4; n++) {
    const unsigned short* mrow = &MT[(n * 16 + l15) * LDP];
    po[n] = __builtin_amdgcn_mfma_f32_16x16x32_bf16(aq0, *(const bf16x8*)(mrow + quad * 8),
                                                    (f32x4){0.f,0.f,0.f,0.f}, 0, 0, 0);
    po[n] = __builtin_amdgcn_mfma_f32_16x16x32_bf16(aq1, *(const bf16x8*)(mrow + 32 + quad * 8),
                                                    po[n], 0, 0, 0);
  }
#pragma unroll
  for (int r = 0; r < 4; r++) {
    int pos = t0 + w * 16 + quad * 4 + r;
    if (pos < L) {
      int t = tl[pos];
      float alpha = alist[(size_t)seg * SEGCAP + pos];
#pragma unroll
      for (int n = 0; n < 4; n++)
        atomicAdd(&out[(size_t)(t * BB + b) * HD + n * 16 + l15], alpha * po[n][r]);
    }
  }
}

// ---------------------------------------------------------------
extern "C" void kernel_launch(void* const* d_in, const int* in_sizes, int n_in,
                              void* d_out, int out_size, void* d_ws, size_t ws_size,
                              hipStream_t stream) {
  const float* X  = (const float*)d_in[0];
  const float* M0 = (const float*)d_in[1];
  const float* Wq = (const float*)d_in[2];
  const float* bq = (const float*)d_in[3];
  const float* Wk = (const float*)d_in[4];
  const float* bk = (const float*)d_in[5];
  const float* Wv = (const float*)d_in[6];
  const float* bv = (const float*)d_in[7];
  const float* Wg = (const float*)d_in[8];
  const float* bg = (const float*)d_in[9];

  char* ws = (char*)d_ws;
  unsigned short* Xbf  = (unsigned short*)(ws);                  // 33,554,432
  unsigned short* Wt   = (unsigned short*)(ws + 33554432ULL);    //  2,621,440
  float*          bcat = (float*)         (ws + 36175872ULL);    //      5,120
  unsigned short* Ocat = (unsigned short*)(ws + 36184064ULL);    // 41,943,040
  unsigned short* Sb16 = (unsigned short*)(ws + 78127104ULL);    // 18,874,368
  int2*           idxb = (int2*)          (ws + 97001472ULL);    //    131,072
  float2*         alfb = (float2*)        (ws + 97132544ULL);    //    131,072
  int*            tlist= (int*)           (ws + 97263616ULL);    //    589,824
  float*          alist= (float*)         (ws + 97853440ULL);    //    589,824
  int*            slen = (int*)           (ws + 98443264ULL);    //        288

  float* out = (float*)d_out;
  hipMemsetAsync(d_out, 0, (size_t)out_size * sizeof(float), stream);

  prep<<<320 + NTOK / 16, 256, 0, stream>>>(X, Wq, Wk, Wv, bq, bk, bv, Wg, bg,
                                            Wt, bcat, idxb, alfb, Xbf);
  pack_kernel<<<NSEG, 256, 0, stream>>>(idxb, alfb, tlist, alist, slen);
  proj_mfma<<<dim3(NTOK / 128, NCAT / 128), 256, 0, stream>>>(Xbf, Wt, bcat, Ocat);
  chunk_intra<<<dim3(NC, NSEG), 256, 0, stream>>>(Ocat, tlist, alist, slen, Sb16, out);
  scan_kernel<<<NSEG * 4, 256, 0, stream>>>(M0, slen, Sb16);
  chunk_inter<<<dim3(NC, NSEG), 256, 0, stream>>>(Ocat, Sb16, tlist, alist, slen, out);
}